// Round 9
// baseline (836.066 us; speedup 1.0000x reference)
//
#include <hip/hip_runtime.h>
#include <hip/hip_bf16.h>

#define N_NODES 50000
#define N_EDGES 1600000
#define IN_CH 64
#define NUM_HID 256
#define NUM_CLASSES 16
#define NUM_GRAPHS 512
#define NBS 196  // ceil(N_NODES/256)

typedef short bf16x8 __attribute__((ext_vector_type(8)));
typedef float f32x4 __attribute__((ext_vector_type(4)));

#if __has_builtin(__builtin_amdgcn_rcpf)
#define RCPF(x) __builtin_amdgcn_rcpf(x)
#else
#define RCPF(x) (1.0f / (x))
#endif

__device__ inline unsigned short f2b(float f) {
    unsigned int u = __float_as_uint(f);
    unsigned int r = (u + 0x7FFF + ((u >> 16) & 1)) >> 16;
    return (unsigned short)r;
}
__device__ inline float b2f(unsigned short u) {
    return __uint_as_float(((unsigned int)u) << 16);
}

// 16B global -> LDS direct (lds dest: wave-uniform base + lane*16)
__device__ inline void gl16(const unsigned short* g, unsigned short* l) {
    __builtin_amdgcn_global_load_lds(
        (const __attribute__((address_space(1))) unsigned int*)g,
        (__attribute__((address_space(3))) unsigned int*)l, 16, 0, 0);
}

// ---------------- preprocessing ----------------
__global__ void prep_w_kernel(const float* __restrict__ wf1, const float* __restrict__ ws1,
                              const float* __restrict__ wf2, const float* __restrict__ ws2,
                              unsigned short* __restrict__ wb1, unsigned short* __restrict__ wb2) {
    int i = blockIdx.x * 256 + threadIdx.x;
    if (i >= 128 * 160) return;
    int r = i / 160, k = i - r * 160;
    wb1[i] = f2b(r < 64 ? wf1[r * 160 + k] : ws1[(r - 64) * 160 + k]);
    wb2[i] = f2b(r < 64 ? wf2[r * 160 + k] : ws2[(r - 64) * 160 + k]);
}

__global__ void prep_x_kernel(const float4* __restrict__ x, unsigned short* __restrict__ xb) {
    int i = blockIdx.x * 256 + threadIdx.x;
    if (i >= N_NODES * 16) return;
    float4 v = x[i];
    ushort4 u; u.x = f2b(v.x); u.y = f2b(v.y); u.z = f2b(v.z); u.w = f2b(v.w);
    *(ushort4*)(xb + i * 4) = u;
}

__global__ void hist_kernel(const int* __restrict__ ei, int* __restrict__ cnt) {
    int i = blockIdx.x * 256 + threadIdx.x;
    if (i < N_EDGES) atomicAdd(&cnt[ei[N_EDGES + i]], 1);
}

__global__ void bsum_kernel(const int* __restrict__ cnt, int* __restrict__ bsum) {
    __shared__ int sm[256];
    int i = blockIdx.x * 256 + threadIdx.x;
    sm[threadIdx.x] = (i < N_NODES) ? cnt[i] : 0;
    __syncthreads();
    for (int off = 128; off > 0; off >>= 1) {
        if (threadIdx.x < off) sm[threadIdx.x] += sm[threadIdx.x + off];
        __syncthreads();
    }
    if (threadIdx.x == 0) bsum[blockIdx.x] = sm[0];
}

__global__ void bscan_kernel(const int* __restrict__ bsum, int* __restrict__ boffs) {
    __shared__ int sm[256];
    int t = threadIdx.x;
    int v = (t < NBS) ? bsum[t] : 0;
    sm[t] = v; __syncthreads();
    for (int off = 1; off < 256; off <<= 1) {
        int u = (t >= off) ? sm[t - off] : 0;
        __syncthreads();
        sm[t] += u;
        __syncthreads();
    }
    if (t < NBS) boffs[t] = sm[t] - v;  // exclusive
}

__global__ void apply_kernel(const int* __restrict__ cnt, const int* __restrict__ boffs,
                             int* __restrict__ cursor, float* __restrict__ invdeg) {
    __shared__ int sm[256];
    int t = threadIdx.x, i = blockIdx.x * 256 + t;
    int c = (i < N_NODES) ? cnt[i] : 0;
    sm[t] = c; __syncthreads();
    for (int off = 1; off < 256; off <<= 1) {
        int u = (t >= off) ? sm[t - off] : 0;
        __syncthreads();
        sm[t] += u;
        __syncthreads();
    }
    if (i < N_NODES) {
        cursor[i] = boffs[blockIdx.x] + sm[t] - c;
        invdeg[i] = 1.0f / fmaxf((float)c, 1.0f);
    }
}

__global__ void scatter_kernel(const int* __restrict__ ei, int* __restrict__ cursor,
                               int2* __restrict__ sed, int* __restrict__ eidx) {
    int e = blockIdx.x * 256 + threadIdx.x;
    if (e >= N_EDGES) return;
    int s = ei[e], d = ei[N_EDGES + e];
    int p = atomicAdd(&cursor[d], 1);
    sed[p] = make_int2(s, d);
    eidx[p] = e;
}

// eab[p] = bf16(ea[eidx[p]]) -- edge_attr pre-sorted to dst-order
__global__ void sortea_kernel(const float* __restrict__ ea, const int* __restrict__ eidx,
                              unsigned short* __restrict__ eab) {
    int i = blockIdx.x * 256 + threadIdx.x;
    if (i >= N_EDGES * 4) return;
    int p = i >> 2, part = i & 3;
    int row = eidx[p];
    const float4* src = (const float4*)(ea + (size_t)row * 32 + part * 8);
    float4 a = src[0], b = src[1];
    ushort4 ua, ub;
    ua.x = f2b(a.x); ua.y = f2b(a.y); ua.z = f2b(a.z); ua.w = f2b(a.w);
    ub.x = f2b(b.x); ub.y = f2b(b.y); ub.z = f2b(b.z); ub.w = f2b(b.w);
    *(ushort4*)(eab + (size_t)p * 32 + part * 8) = ua;
    *(ushort4*)(eab + (size_t)p * 32 + part * 8 + 4) = ub;
}

// ---------------- edge pass (gload_lds variant, EAB required) ----------------
// Zd/Zs: stored chunk c of row e holds data chunk c^(e&7); Ze: c^((e>>1)&3).
// Staging: per wave 5x global_load_lds 1024B windows, source pre-swizzled per lane.
__global__ __launch_bounds__(256, 4)
void edge_mfma_g(const unsigned short* __restrict__ xb,
                 const int2* __restrict__ sed, const unsigned short* __restrict__ eab,
                 const unsigned short* __restrict__ wb,
                 const float* __restrict__ bfv, const float* __restrict__ bsv,
                 float* __restrict__ agg)
{
    __shared__ __align__(16) unsigned short Zd[64 * 64];
    __shared__ __align__(16) unsigned short Zs[64 * 64];
    __shared__ __align__(16) unsigned short Ze[64 * 32];
    __shared__ float msg[64 * 68];
    __shared__ int dstl[2][64];

    const int tid = threadIdx.x;
    const int w = tid >> 6, lane = tid & 63, lr = lane & 15, lq = lane >> 4;
    const int eh = (w >> 1) * 32, chh = (w & 1) * 32;

    bf16x8 B[2][2][5];
    #pragma unroll
    for (int mat = 0; mat < 2; ++mat)
        #pragma unroll
        for (int n = 0; n < 2; ++n)
            #pragma unroll
            for (int ks = 0; ks < 5; ++ks)
                B[mat][n][ks] = *(const bf16x8*)(wb + (size_t)(mat * 64 + chh + n * 16 + lr) * 160 + ks * 32 + lq * 8);

    float biasF[2], biasS[2];
    #pragma unroll
    for (int n = 0; n < 2; ++n) { biasF[n] = bfv[chh + n * 16 + lr]; biasS[n] = bsv[chh + n * 16 + lr]; }

    const int NT = N_EDGES / 64;
    const int nblk = gridDim.x;

    // per-lane source-swizzle geometry (recomputed cheaply; transient)
    // Zd/Zs windows: row_j = w*16 + j*8 + (lane>>3), chunk dc = (lane&7)^(lane>>3)
    // Ze: rowE = w*16 + (lane>>2), dcE = (lane&3)^((lane>>3)&3)

    #define ISSUE_G(T, PAR) do { \
        int e0_ = (T) * 64; \
        int rb_ = w * 16 + (lane >> 3); \
        int dcA_ = (lane & 7) ^ (lane >> 3); \
        int2 s0_ = sed[e0_ + rb_]; \
        int2 s1_ = sed[e0_ + rb_ + 8]; \
        gl16(xb + (size_t)s0_.y * 64 + dcA_ * 8, &Zd[w * 1024]); \
        gl16(xb + (size_t)s1_.y * 64 + dcA_ * 8, &Zd[w * 1024 + 512]); \
        gl16(xb + (size_t)s0_.x * 64 + dcA_ * 8, &Zs[w * 1024]); \
        gl16(xb + (size_t)s1_.x * 64 + dcA_ * 8, &Zs[w * 1024 + 512]); \
        int rE_ = w * 16 + (lane >> 2); \
        int dcE_ = (lane & 3) ^ ((lane >> 3) & 3); \
        gl16(eab + (size_t)(e0_ + rE_) * 32 + dcE_ * 8, &Ze[w * 512]); \
        if (tid < 64) dstl[PAR][tid] = sed[e0_ + tid].y; \
    } while (0)

    int t = blockIdx.x;
    if (t < NT) ISSUE_G(t, 0);
    __syncthreads();  // drains vmcnt -> tile ready
    int par = 0;

    for (; t < NT; t += nblk) {
        // ---- k-loop ----
        f32x4 aF[2][2] = {}; f32x4 aS[2][2] = {};
        const int r0 = eh + lr, r1 = eh + 16 + lr;
        #pragma unroll
        for (int ks = 0; ks < 5; ++ks) {
            bf16x8 a0, a1;
            if (ks < 2) {
                int j = ks * 4 + lq;
                a0 = *(const bf16x8*)&Zd[r0 * 64 + ((j ^ (r0 & 7)) * 8)];
                a1 = *(const bf16x8*)&Zd[r1 * 64 + ((j ^ (r1 & 7)) * 8)];
            } else if (ks < 4) {
                int j = (ks - 2) * 4 + lq;
                a0 = *(const bf16x8*)&Zs[r0 * 64 + ((j ^ (r0 & 7)) * 8)];
                a1 = *(const bf16x8*)&Zs[r1 * 64 + ((j ^ (r1 & 7)) * 8)];
            } else {
                a0 = *(const bf16x8*)&Ze[r0 * 32 + ((lq ^ ((r0 >> 1) & 3)) * 8)];
                a1 = *(const bf16x8*)&Ze[r1 * 32 + ((lq ^ ((r1 >> 1) & 3)) * 8)];
            }
            aF[0][0] = __builtin_amdgcn_mfma_f32_16x16x32_bf16(a0, B[0][0][ks], aF[0][0], 0, 0, 0);
            aF[0][1] = __builtin_amdgcn_mfma_f32_16x16x32_bf16(a0, B[0][1][ks], aF[0][1], 0, 0, 0);
            aF[1][0] = __builtin_amdgcn_mfma_f32_16x16x32_bf16(a1, B[0][0][ks], aF[1][0], 0, 0, 0);
            aF[1][1] = __builtin_amdgcn_mfma_f32_16x16x32_bf16(a1, B[0][1][ks], aF[1][1], 0, 0, 0);
            aS[0][0] = __builtin_amdgcn_mfma_f32_16x16x32_bf16(a0, B[1][0][ks], aS[0][0], 0, 0, 0);
            aS[0][1] = __builtin_amdgcn_mfma_f32_16x16x32_bf16(a0, B[1][1][ks], aS[0][1], 0, 0, 0);
            aS[1][0] = __builtin_amdgcn_mfma_f32_16x16x32_bf16(a1, B[1][0][ks], aS[1][0], 0, 0, 0);
            aS[1][1] = __builtin_amdgcn_mfma_f32_16x16x32_bf16(a1, B[1][1][ks], aS[1][1], 0, 0, 0);
        }
        __syncthreads();  // B2: all waves done reading Z

        int tn = t + nblk;
        if (tn < NT) ISSUE_G(tn, par ^ 1);  // direct-to-LDS prefetch; lands by B3 drain

        // ---- activation -> msg ----
        #pragma unroll
        for (int m = 0; m < 2; ++m)
            #pragma unroll
            for (int n = 0; n < 2; ++n)
                #pragma unroll
                for (int i = 0; i < 4; ++i) {
                    int e = eh + m * 16 + lq * 4 + i;
                    int c = chh + n * 16 + lr;
                    float f = aF[m][n][i] + biasF[n];
                    float s = aS[m][n][i] + biasS[n];
                    float sig = RCPF(1.0f + __expf(-f));
                    float sp = fmaxf(s, 0.0f) + __logf(1.0f + __expf(-fabsf(s)));
                    msg[e * 68 + c] = sig * sp;
                }
        __syncthreads();  // B3

        // ---- run-reduction: wave w owns edges [w*16, w*16+16), channel = lane ----
        {
            float acc = 0.0f;
            int dcur = dstl[par][w * 16];
            #pragma unroll
            for (int j = 0; j < 16; ++j) {
                int e = w * 16 + j;
                int d = dstl[par][e];
                float v = msg[e * 68 + lane];
                if (d != dcur) {
                    atomicAdd(&agg[(size_t)dcur * 64 + lane], acc);
                    dcur = d; acc = v;
                } else {
                    acc += v;
                }
            }
            atomicAdd(&agg[(size_t)dcur * 64 + lane], acc);
        }
        __syncthreads();  // B1
        par ^= 1;
    }
    #undef ISSUE_G
}

// ---------------- fallback edge pass (register-staged, f32 ea gather) ----------------
__global__ __launch_bounds__(256, 2)
void edge_mfma_reg(const unsigned short* __restrict__ xb,
                   const int2* __restrict__ sed, const int* __restrict__ eidx,
                   const float* __restrict__ ea,
                   const unsigned short* __restrict__ wb,
                   const float* __restrict__ bfv, const float* __restrict__ bsv,
                   float* __restrict__ agg)
{
    __shared__ __align__(16) unsigned short Zd[64 * 64];
    __shared__ __align__(16) unsigned short Zs[64 * 64];
    __shared__ __align__(16) unsigned short Ze[64 * 32];
    __shared__ float msg[64 * 68];
    __shared__ int dstl[2][64];

    const int tid = threadIdx.x;
    const int w = tid >> 6, lane = tid & 63, lr = lane & 15, lq = lane >> 4;
    const int eh = (w >> 1) * 32, chh = (w & 1) * 32;

    bf16x8 B[2][2][5];
    #pragma unroll
    for (int mat = 0; mat < 2; ++mat)
        #pragma unroll
        for (int n = 0; n < 2; ++n)
            #pragma unroll
            for (int ks = 0; ks < 5; ++ks)
                B[mat][n][ks] = *(const bf16x8*)(wb + (size_t)(mat * 64 + chh + n * 16 + lr) * 160 + ks * 32 + lq * 8);

    float biasF[2], biasS[2];
    #pragma unroll
    for (int n = 0; n < 2; ++n) { biasF[n] = bfv[chh + n * 16 + lr]; biasS[n] = bsv[chh + n * 16 + lr]; }

    const int rA0 = tid >> 3, cA0 = tid & 7;
    const int rA1 = rA0 + 32;
    const int rE = tid >> 2, cE = tid & 3;
    const int dcA0 = cA0 ^ (rA0 & 7), dcA1 = cA0 ^ (rA1 & 7);
    const int dcE8 = (cE ^ ((rE >> 1) & 3)) * 8;

    const int NT = N_EDGES / 64;
    const int nblk = gridDim.x;

    bf16x8 vd0, vd1, vs0, vs1;
    float4 ve0, ve1;
    int dl = 0;

    #define ISSUE(T) do { \
        int e0_ = (T) * 64; \
        int2 sA0 = sed[e0_ + rA0]; \
        int2 sA1 = sed[e0_ + rA1]; \
        vd0 = *(const bf16x8*)(xb + (size_t)sA0.y * 64 + dcA0 * 8); \
        vd1 = *(const bf16x8*)(xb + (size_t)sA1.y * 64 + dcA1 * 8); \
        vs0 = *(const bf16x8*)(xb + (size_t)sA0.x * 64 + dcA0 * 8); \
        vs1 = *(const bf16x8*)(xb + (size_t)sA1.x * 64 + dcA1 * 8); \
        int ide = eidx[e0_ + rE]; \
        ve0 = *(const float4*)(ea + (size_t)ide * 32 + dcE8); \
        ve1 = *(const float4*)(ea + (size_t)ide * 32 + dcE8 + 4); \
        if (tid < 64) dl = sed[e0_ + tid].y; \
    } while (0)

    #define WRITE(PAR) do { \
        *(bf16x8*)&Zd[rA0 * 64 + cA0 * 8] = vd0; \
        *(bf16x8*)&Zd[rA1 * 64 + cA0 * 8] = vd1; \
        *(bf16x8*)&Zs[rA0 * 64 + cA0 * 8] = vs0; \
        *(bf16x8*)&Zs[rA1 * 64 + cA0 * 8] = vs1; \
        ushort4 ua, ub; \
        ua.x = f2b(ve0.x); ua.y = f2b(ve0.y); ua.z = f2b(ve0.z); ua.w = f2b(ve0.w); \
        ub.x = f2b(ve1.x); ub.y = f2b(ve1.y); ub.z = f2b(ve1.z); ub.w = f2b(ve1.w); \
        *(ushort4*)&Ze[rE * 32 + cE * 8] = ua; \
        *(ushort4*)&Ze[rE * 32 + cE * 8 + 4] = ub; \
        if (tid < 64) dstl[PAR][tid] = dl; \
    } while (0)

    int t = blockIdx.x;
    if (t < NT) { ISSUE(t); WRITE(0); }
    __syncthreads();
    int par = 0;

    for (; t < NT; t += nblk) {
        int tn = t + nblk;
        bool pf = tn < NT;
        if (pf) ISSUE(tn);

        f32x4 aF[2][2] = {}; f32x4 aS[2][2] = {};
        const int r0 = eh + lr, r1 = eh + 16 + lr;
        #pragma unroll
        for (int ks = 0; ks < 5; ++ks) {
            bf16x8 a0, a1;
            if (ks < 2) {
                int j = ks * 4 + lq;
                a0 = *(const bf16x8*)&Zd[r0 * 64 + ((j ^ (r0 & 7)) * 8)];
                a1 = *(const bf16x8*)&Zd[r1 * 64 + ((j ^ (r1 & 7)) * 8)];
            } else if (ks < 4) {
                int j = (ks - 2) * 4 + lq;
                a0 = *(const bf16x8*)&Zs[r0 * 64 + ((j ^ (r0 & 7)) * 8)];
                a1 = *(const bf16x8*)&Zs[r1 * 64 + ((j ^ (r1 & 7)) * 8)];
            } else {
                a0 = *(const bf16x8*)&Ze[r0 * 32 + ((lq ^ ((r0 >> 1) & 3)) * 8)];
                a1 = *(const bf16x8*)&Ze[r1 * 32 + ((lq ^ ((r1 >> 1) & 3)) * 8)];
            }
            aF[0][0] = __builtin_amdgcn_mfma_f32_16x16x32_bf16(a0, B[0][0][ks], aF[0][0], 0, 0, 0);
            aF[0][1] = __builtin_amdgcn_mfma_f32_16x16x32_bf16(a0, B[0][1][ks], aF[0][1], 0, 0, 0);
            aF[1][0] = __builtin_amdgcn_mfma_f32_16x16x32_bf16(a1, B[0][0][ks], aF[1][0], 0, 0, 0);
            aF[1][1] = __builtin_amdgcn_mfma_f32_16x16x32_bf16(a1, B[0][1][ks], aF[1][1], 0, 0, 0);
            aS[0][0] = __builtin_amdgcn_mfma_f32_16x16x32_bf16(a0, B[1][0][ks], aS[0][0], 0, 0, 0);
            aS[0][1] = __builtin_amdgcn_mfma_f32_16x16x32_bf16(a0, B[1][1][ks], aS[0][1], 0, 0, 0);
            aS[1][0] = __builtin_amdgcn_mfma_f32_16x16x32_bf16(a1, B[1][0][ks], aS[1][0], 0, 0, 0);
            aS[1][1] = __builtin_amdgcn_mfma_f32_16x16x32_bf16(a1, B[1][1][ks], aS[1][1], 0, 0, 0);
        }
        __syncthreads();

        #pragma unroll
        for (int m = 0; m < 2; ++m)
            #pragma unroll
            for (int n = 0; n < 2; ++n)
                #pragma unroll
                for (int i = 0; i < 4; ++i) {
                    int e = eh + m * 16 + lq * 4 + i;
                    int c = chh + n * 16 + lr;
                    float f = aF[m][n][i] + biasF[n];
                    float s = aS[m][n][i] + biasS[n];
                    float sig = RCPF(1.0f + __expf(-f));
                    float sp = fmaxf(s, 0.0f) + __logf(1.0f + __expf(-fabsf(s)));
                    msg[e * 68 + c] = sig * sp;
                }
        __syncthreads();

        {
            float acc = 0.0f;
            int dcur = dstl[par][w * 16];
            #pragma unroll
            for (int j = 0; j < 16; ++j) {
                int e = w * 16 + j;
                int d = dstl[par][e];
                float v = msg[e * 68 + lane];
                if (d != dcur) {
                    atomicAdd(&agg[(size_t)dcur * 64 + lane], acc);
                    dcur = d; acc = v;
                } else {
                    acc += v;
                }
            }
            atomicAdd(&agg[(size_t)dcur * 64 + lane], acc);
        }

        if (pf) WRITE(par ^ 1);
        __syncthreads();
        par ^= 1;
    }
    #undef ISSUE
    #undef WRITE
}

// ---------------- residual: hb = bf16(agg*inv_deg + x) ----------------
__global__ void resid2_kernel(const float4* __restrict__ agg, const float* __restrict__ inv_deg,
                              const float4* __restrict__ x, unsigned short* __restrict__ hb)
{
    int i = blockIdx.x * 256 + threadIdx.x;
    if (i >= N_NODES * 16) return;
    int n = i >> 4;
    float iv = inv_deg[n];
    float4 a = agg[i], xv = x[i];
    ushort4 u;
    u.x = f2b(a.x * iv + xv.x); u.y = f2b(a.y * iv + xv.y);
    u.z = f2b(a.z * iv + xv.z); u.w = f2b(a.w * iv + xv.w);
    *(ushort4*)(hb + i * 4) = u;
}

// ---------------- layer-2 residual fused with graph pooling (+ gcnt fused) ----------------
__global__ void pool2_kernel(const float4* __restrict__ agg, const float* __restrict__ inv_deg,
                             const unsigned short* __restrict__ hb, const int* __restrict__ batch,
                             float* __restrict__ gsum, float* __restrict__ gcnt)
{
    int i = blockIdx.x * 256 + threadIdx.x;
    if (i >= N_NODES * 16) return;
    int n = i >> 4;
    int g = batch[n];
    float iv = inv_deg[n];
    float4 a = agg[i];
    ushort4 hu = *(const ushort4*)(hb + i * 4);
    int base = g * 64 + (i & 15) * 4;
    atomicAdd(&gsum[base + 0], a.x * iv + b2f(hu.x));
    atomicAdd(&gsum[base + 1], a.y * iv + b2f(hu.y));
    atomicAdd(&gsum[base + 2], a.z * iv + b2f(hu.z));
    atomicAdd(&gsum[base + 3], a.w * iv + b2f(hu.w));
    if ((i & 15) == 0) atomicAdd(&gcnt[g], 1.0f);
}

// ---------------- head: MLP + log_softmax ----------------
__global__ __launch_bounds__(64)
void head_kernel(const float* __restrict__ gsum, const float* __restrict__ gcnt,
                 const float* __restrict__ w1, const float* __restrict__ b1,
                 const float* __restrict__ w2, const float* __restrict__ b2,
                 float* __restrict__ out)
{
    __shared__ float gv[64];
    __shared__ float hid[256];
    __shared__ float outv[16];
    const int g = blockIdx.x, t = threadIdx.x;
    float cnt = fmaxf(gcnt[g], 1.0f);
    gv[t] = gsum[g * 64 + t] / cnt;
    __syncthreads();
    #pragma unroll
    for (int r = 0; r < 4; ++r) {
        int c = t + r * 64;
        float acc = b1[c];
        const float4* wr = (const float4*)(w1 + c * 64);
        const float4* gvv = (const float4*)gv;
        #pragma unroll
        for (int k = 0; k < 16; ++k) {
            float4 wv = wr[k], xv = gvv[k];
            acc += wv.x * xv.x + wv.y * xv.y + wv.z * xv.z + wv.w * xv.w;
        }
        hid[c] = fmaxf(acc, 0.0f);
    }
    __syncthreads();
    if (t < 16) {
        float acc = b2[t];
        const float4* wr = (const float4*)(w2 + t * 256);
        const float4* hv = (const float4*)hid;
        for (int k = 0; k < 64; ++k) {
            float4 wv = wr[k], xv = hv[k];
            acc += wv.x * xv.x + wv.y * xv.y + wv.z * xv.z + wv.w * xv.w;
        }
        outv[t] = acc;
    }
    __syncthreads();
    if (t < 16) {
        float m = outv[0];
        #pragma unroll
        for (int j = 1; j < 16; ++j) m = fmaxf(m, outv[j]);
        float ssum = 0.0f;
        #pragma unroll
        for (int j = 0; j < 16; ++j) ssum += expf(outv[j] - m);
        out[g * 16 + t] = outv[t] - m - logf(ssum);
    }
}

extern "C" void kernel_launch(void* const* d_in, const int* in_sizes, int n_in,
                              void* d_out, int out_size, void* d_ws, size_t ws_size,
                              hipStream_t stream)
{
    const float* x     = (const float*)d_in[0];
    const int*   ei    = (const int*)d_in[1];
    const float* ea    = (const float*)d_in[2];
    const int*   batch = (const int*)d_in[3];
    const float* wf1 = (const float*)d_in[4];
    const float* bf1 = (const float*)d_in[5];
    const float* ws1 = (const float*)d_in[6];
    const float* bs1 = (const float*)d_in[7];
    const float* wf2 = (const float*)d_in[8];
    const float* bf2 = (const float*)d_in[9];
    const float* ws2 = (const float*)d_in[10];
    const float* bs2 = (const float*)d_in[11];
    const float* w1 = (const float*)d_in[12];
    const float* b1 = (const float*)d_in[13];
    const float* w2 = (const float*)d_in[14];
    const float* b2 = (const float*)d_in[15];
    float* out = (float*)d_out;

    char* ws = (char*)d_ws;
    int*   cnt    = (int*)(ws + 0x0000000);           // 200 KB
    int*   cursor = (int*)(ws + 0x0040000);           // 200 KB
    float* invdeg = (float*)(ws + 0x0080000);         // 200 KB
    int*   bsum   = (int*)(ws + 0x00C0000);           // 1 KB
    int*   boffs  = (int*)(ws + 0x00C1000);           // 1 KB
    int2*  sed    = (int2*)(ws + 0x0100000);          // 12.8 MB
    int*   eidx   = (int*)(ws + 0x0E00000);           // 6.4 MB
    unsigned short* xb  = (unsigned short*)(ws + 0x1500000);  // 6.4 MB
    unsigned short* hb  = (unsigned short*)(ws + 0x1C00000);  // 6.4 MB
    float* agg = (float*)(ws + 0x2300000);            // 12.8 MB
    unsigned short* wb1 = (unsigned short*)(ws + 0x3000000);  // 40 KB
    unsigned short* wb2 = (unsigned short*)(ws + 0x3010000);  // 40 KB
    float* gsum = (float*)(ws + 0x3020000);           // 128 KB
    float* gcnt = (float*)(ws + 0x3040000);           // 2 KB
    unsigned short* eab = (unsigned short*)(ws + 0x3100000);  // 102.4 MB (optional)
    const bool use_eab = ws_size >= (size_t)0x9320000;

    hipMemsetAsync(cnt, 0, 200000, stream);
    hipMemsetAsync(agg, 0, 12800000, stream);
    hipMemsetAsync(gsum, 0, 131072 + 2048, stream);

    prep_w_kernel<<<80, 256, 0, stream>>>(wf1, ws1, wf2, ws2, wb1, wb2);
    prep_x_kernel<<<3125, 256, 0, stream>>>((const float4*)x, xb);
    hist_kernel<<<6250, 256, 0, stream>>>(ei, cnt);
    bsum_kernel<<<NBS, 256, 0, stream>>>(cnt, bsum);
    bscan_kernel<<<1, 256, 0, stream>>>(bsum, boffs);
    apply_kernel<<<NBS, 256, 0, stream>>>(cnt, boffs, cursor, invdeg);
    scatter_kernel<<<6250, 256, 0, stream>>>(ei, cursor, sed, eidx);

    if (use_eab) {
        sortea_kernel<<<25000, 256, 0, stream>>>(ea, eidx, eab);
        edge_mfma_g<<<1024, 256, 0, stream>>>(xb, sed, eab, wb1, bf1, bs1, agg);
        resid2_kernel<<<3125, 256, 0, stream>>>((const float4*)agg, invdeg, (const float4*)x, hb);
        hipMemsetAsync(agg, 0, 12800000, stream);
        edge_mfma_g<<<1024, 256, 0, stream>>>(hb, sed, eab, wb2, bf2, bs2, agg);
    } else {
        edge_mfma_reg<<<1024, 256, 0, stream>>>(xb, sed, eidx, ea, wb1, bf1, bs1, agg);
        resid2_kernel<<<3125, 256, 0, stream>>>((const float4*)agg, invdeg, (const float4*)x, hb);
        hipMemsetAsync(agg, 0, 12800000, stream);
        edge_mfma_reg<<<1024, 256, 0, stream>>>(hb, sed, eidx, ea, wb2, bf2, bs2, agg);
    }
    pool2_kernel<<<3125, 256, 0, stream>>>((const float4*)agg, invdeg, hb, batch, gsum, gcnt);
    head_kernel<<<NUM_GRAPHS, 64, 0, stream>>>(gsum, gcnt, w1, b1, w2, b2, out);
}

// Round 10
// 683.259 us; speedup vs baseline: 1.2236x; 1.2236x over previous
//
#include <hip/hip_runtime.h>
#include <hip/hip_bf16.h>

#define N_NODES 50000
#define N_EDGES 1600000
#define IN_CH 64
#define NUM_HID 256
#define NUM_CLASSES 16
#define NUM_GRAPHS 512
#define NBS 196  // ceil(N_NODES/256)

typedef short bf16x8 __attribute__((ext_vector_type(8)));
typedef float f32x4 __attribute__((ext_vector_type(4)));

#if __has_builtin(__builtin_amdgcn_rcpf)
#define RCPF(x) __builtin_amdgcn_rcpf(x)
#else
#define RCPF(x) (1.0f / (x))
#endif

__device__ inline unsigned short f2b(float f) {
    unsigned int u = __float_as_uint(f);
    unsigned int r = (u + 0x7FFF + ((u >> 16) & 1)) >> 16;
    return (unsigned short)r;
}
__device__ inline float b2f(unsigned short u) {
    return __uint_as_float(((unsigned int)u) << 16);
}

// ---------------- preprocessing ----------------
__global__ void prep_w_kernel(const float* __restrict__ wf1, const float* __restrict__ ws1,
                              const float* __restrict__ wf2, const float* __restrict__ ws2,
                              unsigned short* __restrict__ wb1, unsigned short* __restrict__ wb2) {
    int i = blockIdx.x * 256 + threadIdx.x;
    if (i >= 128 * 160) return;
    int r = i / 160, k = i - r * 160;
    wb1[i] = f2b(r < 64 ? wf1[r * 160 + k] : ws1[(r - 64) * 160 + k]);
    wb2[i] = f2b(r < 64 ? wf2[r * 160 + k] : ws2[(r - 64) * 160 + k]);
}

__global__ void prep_x_kernel(const float4* __restrict__ x, unsigned short* __restrict__ xb) {
    int i = blockIdx.x * 256 + threadIdx.x;
    if (i >= N_NODES * 16) return;
    float4 v = x[i];
    ushort4 u; u.x = f2b(v.x); u.y = f2b(v.y); u.z = f2b(v.z); u.w = f2b(v.w);
    *(ushort4*)(xb + i * 4) = u;
}

__global__ void hist_kernel(const int* __restrict__ ei, int* __restrict__ cnt) {
    int i = blockIdx.x * 256 + threadIdx.x;
    if (i < N_EDGES) atomicAdd(&cnt[ei[N_EDGES + i]], 1);
}

__global__ void bsum_kernel(const int* __restrict__ cnt, int* __restrict__ bsum) {
    __shared__ int sm[256];
    int i = blockIdx.x * 256 + threadIdx.x;
    sm[threadIdx.x] = (i < N_NODES) ? cnt[i] : 0;
    __syncthreads();
    for (int off = 128; off > 0; off >>= 1) {
        if (threadIdx.x < off) sm[threadIdx.x] += sm[threadIdx.x + off];
        __syncthreads();
    }
    if (threadIdx.x == 0) bsum[blockIdx.x] = sm[0];
}

__global__ void bscan_kernel(const int* __restrict__ bsum, int* __restrict__ boffs) {
    __shared__ int sm[256];
    int t = threadIdx.x;
    int v = (t < NBS) ? bsum[t] : 0;
    sm[t] = v; __syncthreads();
    for (int off = 1; off < 256; off <<= 1) {
        int u = (t >= off) ? sm[t - off] : 0;
        __syncthreads();
        sm[t] += u;
        __syncthreads();
    }
    if (t < NBS) boffs[t] = sm[t] - v;  // exclusive
}

__global__ void apply_kernel(const int* __restrict__ cnt, const int* __restrict__ boffs,
                             int* __restrict__ cursor, float* __restrict__ invdeg) {
    __shared__ int sm[256];
    int t = threadIdx.x, i = blockIdx.x * 256 + t;
    int c = (i < N_NODES) ? cnt[i] : 0;
    sm[t] = c; __syncthreads();
    for (int off = 1; off < 256; off <<= 1) {
        int u = (t >= off) ? sm[t - off] : 0;
        __syncthreads();
        sm[t] += u;
        __syncthreads();
    }
    if (i < N_NODES) {
        cursor[i] = boffs[blockIdx.x] + sm[t] - c;
        invdeg[i] = 1.0f / fmaxf((float)c, 1.0f);
    }
}

// scatter + in-place sort of edge_attr to dst-order (bf16), fused
__global__ void scatter_kernel(const int* __restrict__ ei, int* __restrict__ cursor,
                               const float* __restrict__ ea,
                               int2* __restrict__ sed, unsigned short* __restrict__ eab) {
    int e = blockIdx.x * 256 + threadIdx.x;
    if (e >= N_EDGES) return;
    int s = ei[e], d = ei[N_EDGES + e];
    int p = atomicAdd(&cursor[d], 1);
    sed[p] = make_int2(s, d);
    const float4* src = (const float4*)(ea + (size_t)e * 32);
    unsigned short* dst = eab + (size_t)p * 32;
    #pragma unroll
    for (int j = 0; j < 8; ++j) {
        float4 v = src[j];
        ushort4 u; u.x = f2b(v.x); u.y = f2b(v.y); u.z = f2b(v.z); u.w = f2b(v.w);
        *(ushort4*)(dst + j * 4) = u;
    }
}

// ---------------- edge pass: single lgkm-barrier per tile ----------------
// Double-buffered Z; msg/reduce wave-private (each wave reduces its own 32x32 quadrant);
// raw s_barrier + lgkmcnt(0) only -> atomics and gathers never drain at barriers.
__global__ __launch_bounds__(256, 2)
void edge_mfma(const unsigned short* __restrict__ xb,
               const int2* __restrict__ sed, const unsigned short* __restrict__ eab,
               const unsigned short* __restrict__ wb,
               const float* __restrict__ bfv, const float* __restrict__ bsv,
               float* __restrict__ agg)
{
    __shared__ __align__(16) unsigned short Zd[2][64 * 64];  // chunk c of row e holds data chunk c^(e&7)
    __shared__ __align__(16) unsigned short Zs[2][64 * 64];
    __shared__ __align__(16) unsigned short Ze[2][64 * 32];  // chunk c holds data chunk c^((e>>1)&3)
    __shared__ float msg[64 * 68];                           // wave-private quadrant regions
    __shared__ int dstl[2][64];

    const int tid = threadIdx.x;
    const int w = tid >> 6, lane = tid & 63, lr = lane & 15, lq = lane >> 4;
    const int eh = (w >> 1) * 32, chh = (w & 1) * 32;

    bf16x8 B[2][2][5];
    #pragma unroll
    for (int mat = 0; mat < 2; ++mat)
        #pragma unroll
        for (int n = 0; n < 2; ++n)
            #pragma unroll
            for (int ks = 0; ks < 5; ++ks)
                B[mat][n][ks] = *(const bf16x8*)(wb + (size_t)(mat * 64 + chh + n * 16 + lr) * 160 + ks * 32 + lq * 8);

    float biasF[2], biasS[2];
    #pragma unroll
    for (int n = 0; n < 2; ++n) { biasF[n] = bfv[chh + n * 16 + lr]; biasS[n] = bsv[chh + n * 16 + lr]; }

    const int rA0 = tid >> 3, cA0 = tid & 7;
    const int rA1 = rA0 + 32;
    const int rE = tid >> 2, cE = tid & 3;
    const int dcA0 = cA0 ^ (rA0 & 7), dcA1 = cA0 ^ (rA1 & 7);
    const int dcE8 = (cE ^ ((rE >> 1) & 3)) * 8;

    const int NT = N_EDGES / 64;
    const int nblk = gridDim.x;

    bf16x8 vd0, vd1, vs0, vs1, veb;
    int dl = 0;

    #define ISSUE(T) do { \
        int e0_ = (T) * 64; \
        int2 sA0 = sed[e0_ + rA0]; \
        int2 sA1 = sed[e0_ + rA1]; \
        vd0 = *(const bf16x8*)(xb + (size_t)sA0.y * 64 + dcA0 * 8); \
        vd1 = *(const bf16x8*)(xb + (size_t)sA1.y * 64 + dcA1 * 8); \
        vs0 = *(const bf16x8*)(xb + (size_t)sA0.x * 64 + dcA0 * 8); \
        vs1 = *(const bf16x8*)(xb + (size_t)sA1.x * 64 + dcA1 * 8); \
        veb = *(const bf16x8*)(eab + (size_t)(e0_ + rE) * 32 + dcE8); \
        if (tid < 64) dl = sed[e0_ + tid].y; \
    } while (0)

    #define WRITE(PAR) do { \
        *(bf16x8*)&Zd[PAR][rA0 * 64 + cA0 * 8] = vd0; \
        *(bf16x8*)&Zd[PAR][rA1 * 64 + cA0 * 8] = vd1; \
        *(bf16x8*)&Zs[PAR][rA0 * 64 + cA0 * 8] = vs0; \
        *(bf16x8*)&Zs[PAR][rA1 * 64 + cA0 * 8] = vs1; \
        *(bf16x8*)&Ze[PAR][rE * 32 + cE * 8] = veb; \
        if (tid < 64) dstl[PAR][tid] = dl; \
    } while (0)

    #define SOFT_BARRIER() do { \
        asm volatile("s_waitcnt lgkmcnt(0)" ::: "memory"); \
        __builtin_amdgcn_s_barrier(); \
    } while (0)

    int t = blockIdx.x;
    if (t < NT) { ISSUE(t); WRITE(0); }
    SOFT_BARRIER();  // compiler-counted vmcnt covers reg uses inside WRITE
    int par = 0;

    for (; t < NT; t += nblk) {
        int tn = t + nblk;
        bool pf = tn < NT;
        if (pf) ISSUE(tn);  // gathers land during k-loop + act + reduce

        // ---- k-loop (reads buf[par]) ----
        f32x4 aF[2][2] = {}; f32x4 aS[2][2] = {};
        const int r0 = eh + lr, r1 = eh + 16 + lr;
        #pragma unroll
        for (int ks = 0; ks < 5; ++ks) {
            bf16x8 a0, a1;
            if (ks < 2) {
                int j = ks * 4 + lq;
                a0 = *(const bf16x8*)&Zd[par][r0 * 64 + ((j ^ (r0 & 7)) * 8)];
                a1 = *(const bf16x8*)&Zd[par][r1 * 64 + ((j ^ (r1 & 7)) * 8)];
            } else if (ks < 4) {
                int j = (ks - 2) * 4 + lq;
                a0 = *(const bf16x8*)&Zs[par][r0 * 64 + ((j ^ (r0 & 7)) * 8)];
                a1 = *(const bf16x8*)&Zs[par][r1 * 64 + ((j ^ (r1 & 7)) * 8)];
            } else {
                a0 = *(const bf16x8*)&Ze[par][r0 * 32 + ((lq ^ ((r0 >> 1) & 3)) * 8)];
                a1 = *(const bf16x8*)&Ze[par][r1 * 32 + ((lq ^ ((r1 >> 1) & 3)) * 8)];
            }
            aF[0][0] = __builtin_amdgcn_mfma_f32_16x16x32_bf16(a0, B[0][0][ks], aF[0][0], 0, 0, 0);
            aF[0][1] = __builtin_amdgcn_mfma_f32_16x16x32_bf16(a0, B[0][1][ks], aF[0][1], 0, 0, 0);
            aF[1][0] = __builtin_amdgcn_mfma_f32_16x16x32_bf16(a1, B[0][0][ks], aF[1][0], 0, 0, 0);
            aF[1][1] = __builtin_amdgcn_mfma_f32_16x16x32_bf16(a1, B[0][1][ks], aF[1][1], 0, 0, 0);
            aS[0][0] = __builtin_amdgcn_mfma_f32_16x16x32_bf16(a0, B[1][0][ks], aS[0][0], 0, 0, 0);
            aS[0][1] = __builtin_amdgcn_mfma_f32_16x16x32_bf16(a0, B[1][1][ks], aS[0][1], 0, 0, 0);
            aS[1][0] = __builtin_amdgcn_mfma_f32_16x16x32_bf16(a1, B[1][0][ks], aS[1][0], 0, 0, 0);
            aS[1][1] = __builtin_amdgcn_mfma_f32_16x16x32_bf16(a1, B[1][1][ks], aS[1][1], 0, 0, 0);
        }

        // ---- activation -> msg (wave-private quadrant: edges [eh,eh+32) x ch [chh,chh+32)) ----
        #pragma unroll
        for (int m = 0; m < 2; ++m)
            #pragma unroll
            for (int n = 0; n < 2; ++n)
                #pragma unroll
                for (int i = 0; i < 4; ++i) {
                    int e = eh + m * 16 + lq * 4 + i;
                    int c = chh + n * 16 + lr;
                    float f = aF[m][n][i] + biasF[n];
                    float s = aS[m][n][i] + biasS[n];
                    float sig = RCPF(1.0f + __expf(-f));
                    float sp = fmaxf(s, 0.0f) + __logf(1.0f + __expf(-fabsf(s)));
                    msg[e * 68 + c] = sig * sp;
                }

        // ---- run-reduction, wave-private: half-wave h reduces edges [eh+h*16, +16) over ch [chh, chh+32) ----
        {
            int half = lane >> 5;
            int ch = chh + (lane & 31);
            int ebase = eh + half * 16;
            float acc = 0.0f;
            int dcur = dstl[par][ebase];
            #pragma unroll
            for (int j = 0; j < 16; ++j) {
                int e = ebase + j;
                int d = dstl[par][e];
                float v = msg[e * 68 + ch];
                if (d != dcur) {
                    atomicAdd(&agg[(size_t)dcur * 64 + ch], acc);
                    dcur = d; acc = v;
                } else {
                    acc += v;
                }
            }
            atomicAdd(&agg[(size_t)dcur * 64 + ch], acc);
        }

        if (pf) WRITE(par ^ 1);
        SOFT_BARRIER();  // lgkm only: staged LDS visible; atomics/gathers stay in flight
        par ^= 1;
    }
    #undef ISSUE
    #undef WRITE
    #undef SOFT_BARRIER
}

// ---------------- residual: hb = bf16(agg*inv_deg + x) ----------------
__global__ void resid2_kernel(const float4* __restrict__ agg, const float* __restrict__ inv_deg,
                              const float4* __restrict__ x, unsigned short* __restrict__ hb)
{
    int i = blockIdx.x * 256 + threadIdx.x;
    if (i >= N_NODES * 16) return;
    int n = i >> 4;
    float iv = inv_deg[n];
    float4 a = agg[i], xv = x[i];
    ushort4 u;
    u.x = f2b(a.x * iv + xv.x); u.y = f2b(a.y * iv + xv.y);
    u.z = f2b(a.z * iv + xv.z); u.w = f2b(a.w * iv + xv.w);
    *(ushort4*)(hb + i * 4) = u;
}

// ---------------- layer-2 residual fused with graph pooling (+ gcnt fused) ----------------
__global__ void pool2_kernel(const float4* __restrict__ agg, const float* __restrict__ inv_deg,
                             const unsigned short* __restrict__ hb, const int* __restrict__ batch,
                             float* __restrict__ gsum, float* __restrict__ gcnt)
{
    int i = blockIdx.x * 256 + threadIdx.x;
    if (i >= N_NODES * 16) return;
    int n = i >> 4;
    int g = batch[n];
    float iv = inv_deg[n];
    float4 a = agg[i];
    ushort4 hu = *(const ushort4*)(hb + i * 4);
    int base = g * 64 + (i & 15) * 4;
    atomicAdd(&gsum[base + 0], a.x * iv + b2f(hu.x));
    atomicAdd(&gsum[base + 1], a.y * iv + b2f(hu.y));
    atomicAdd(&gsum[base + 2], a.z * iv + b2f(hu.z));
    atomicAdd(&gsum[base + 3], a.w * iv + b2f(hu.w));
    if ((i & 15) == 0) atomicAdd(&gcnt[g], 1.0f);
}

// ---------------- head: MLP + log_softmax ----------------
__global__ __launch_bounds__(64)
void head_kernel(const float* __restrict__ gsum, const float* __restrict__ gcnt,
                 const float* __restrict__ w1, const float* __restrict__ b1,
                 const float* __restrict__ w2, const float* __restrict__ b2,
                 float* __restrict__ out)
{
    __shared__ float gv[64];
    __shared__ float hid[256];
    __shared__ float outv[16];
    const int g = blockIdx.x, t = threadIdx.x;
    float cnt = fmaxf(gcnt[g], 1.0f);
    gv[t] = gsum[g * 64 + t] / cnt;
    __syncthreads();
    #pragma unroll
    for (int r = 0; r < 4; ++r) {
        int c = t + r * 64;
        float acc = b1[c];
        const float4* wr = (const float4*)(w1 + c * 64);
        const float4* gvv = (const float4*)gv;
        #pragma unroll
        for (int k = 0; k < 16; ++k) {
            float4 wv = wr[k], xv = gvv[k];
            acc += wv.x * xv.x + wv.y * xv.y + wv.z * xv.z + wv.w * xv.w;
        }
        hid[c] = fmaxf(acc, 0.0f);
    }
    __syncthreads();
    if (t < 16) {
        float acc = b2[t];
        const float4* wr = (const float4*)(w2 + t * 256);
        const float4* hv = (const float4*)hid;
        for (int k = 0; k < 64; ++k) {
            float4 wv = wr[k], xv = hv[k];
            acc += wv.x * xv.x + wv.y * xv.y + wv.z * xv.z + wv.w * xv.w;
        }
        outv[t] = acc;
    }
    __syncthreads();
    if (t < 16) {
        float m = outv[0];
        #pragma unroll
        for (int j = 1; j < 16; ++j) m = fmaxf(m, outv[j]);
        float ssum = 0.0f;
        #pragma unroll
        for (int j = 0; j < 16; ++j) ssum += expf(outv[j] - m);
        out[g * 16 + t] = outv[t] - m - logf(ssum);
    }
}

extern "C" void kernel_launch(void* const* d_in, const int* in_sizes, int n_in,
                              void* d_out, int out_size, void* d_ws, size_t ws_size,
                              hipStream_t stream)
{
    const float* x     = (const float*)d_in[0];
    const int*   ei    = (const int*)d_in[1];
    const float* ea    = (const float*)d_in[2];
    const int*   batch = (const int*)d_in[3];
    const float* wf1 = (const float*)d_in[4];
    const float* bf1 = (const float*)d_in[5];
    const float* ws1 = (const float*)d_in[6];
    const float* bs1 = (const float*)d_in[7];
    const float* wf2 = (const float*)d_in[8];
    const float* bf2 = (const float*)d_in[9];
    const float* ws2 = (const float*)d_in[10];
    const float* bs2 = (const float*)d_in[11];
    const float* w1 = (const float*)d_in[12];
    const float* b1 = (const float*)d_in[13];
    const float* w2 = (const float*)d_in[14];
    const float* b2 = (const float*)d_in[15];
    float* out = (float*)d_out;

    char* ws = (char*)d_ws;
    int*   cnt    = (int*)(ws + 0x0000000);           // 200 KB
    int*   cursor = (int*)(ws + 0x0040000);           // 200 KB
    float* invdeg = (float*)(ws + 0x0080000);         // 200 KB
    int*   bsum   = (int*)(ws + 0x00C0000);           // 1 KB
    int*   boffs  = (int*)(ws + 0x00C1000);           // 1 KB
    int2*  sed    = (int2*)(ws + 0x0100000);          // 12.8 MB
    unsigned short* xb  = (unsigned short*)(ws + 0x1500000);  // 6.4 MB
    unsigned short* hb  = (unsigned short*)(ws + 0x1C00000);  // 6.4 MB
    float* agg = (float*)(ws + 0x2300000);            // 12.8 MB
    unsigned short* wb1 = (unsigned short*)(ws + 0x3000000);  // 40 KB
    unsigned short* wb2 = (unsigned short*)(ws + 0x3010000);  // 40 KB
    float* gsum = (float*)(ws + 0x3020000);           // 128 KB
    float* gcnt = (float*)(ws + 0x3040000);           // 2 KB
    unsigned short* eab = (unsigned short*)(ws + 0x3100000);  // 102.4 MB (verified fits: rounds 8-9 ran this path)

    hipMemsetAsync(cnt, 0, 200000, stream);
    hipMemsetAsync(agg, 0, 12800000, stream);
    hipMemsetAsync(gsum, 0, 131072 + 2048, stream);

    prep_w_kernel<<<80, 256, 0, stream>>>(wf1, ws1, wf2, ws2, wb1, wb2);
    prep_x_kernel<<<3125, 256, 0, stream>>>((const float4*)x, xb);
    hist_kernel<<<6250, 256, 0, stream>>>(ei, cnt);
    bsum_kernel<<<NBS, 256, 0, stream>>>(cnt, bsum);
    bscan_kernel<<<1, 256, 0, stream>>>(bsum, boffs);
    apply_kernel<<<NBS, 256, 0, stream>>>(cnt, boffs, cursor, invdeg);
    scatter_kernel<<<6250, 256, 0, stream>>>(ei, cursor, ea, sed, eab);

    edge_mfma<<<1024, 256, 0, stream>>>(xb, sed, eab, wb1, bf1, bs1, agg);
    resid2_kernel<<<3125, 256, 0, stream>>>((const float4*)agg, invdeg, (const float4*)x, hb);
    hipMemsetAsync(agg, 0, 12800000, stream);
    edge_mfma<<<1024, 256, 0, stream>>>(hb, sed, eab, wb2, bf2, bs2, agg);
    pool2_kernel<<<3125, 256, 0, stream>>>((const float4*)agg, invdeg, hb, batch, gsum, gcnt);
    head_kernel<<<NUM_GRAPHS, 64, 0, stream>>>(gsum, gcnt, w1, b1, w2, b2, out);
}

// Round 11
// 610.362 us; speedup vs baseline: 1.3698x; 1.1194x over previous
//
#include <hip/hip_runtime.h>
#include <hip/hip_bf16.h>

#define N_NODES 50000
#define N_EDGES 1600000
#define IN_CH 64
#define NUM_HID 256
#define NUM_CLASSES 16
#define NUM_GRAPHS 512
#define NBS 196  // ceil(N_NODES/256)

typedef short bf16x8 __attribute__((ext_vector_type(8)));
typedef float f32x4 __attribute__((ext_vector_type(4)));

#if __has_builtin(__builtin_amdgcn_rcpf)
#define RCPF(x) __builtin_amdgcn_rcpf(x)
#else
#define RCPF(x) (1.0f / (x))
#endif

__device__ inline unsigned short f2b(float f) {
    unsigned int u = __float_as_uint(f);
    unsigned int r = (u + 0x7FFF + ((u >> 16) & 1)) >> 16;
    return (unsigned short)r;
}
__device__ inline float b2f(unsigned short u) {
    return __uint_as_float(((unsigned int)u) << 16);
}

// ---------------- preprocessing ----------------
__global__ void prep_w_kernel(const float* __restrict__ wf1, const float* __restrict__ ws1,
                              const float* __restrict__ wf2, const float* __restrict__ ws2,
                              unsigned short* __restrict__ wb1, unsigned short* __restrict__ wb2) {
    int i = blockIdx.x * 256 + threadIdx.x;
    if (i >= 128 * 160) return;
    int r = i / 160, k = i - r * 160;
    wb1[i] = f2b(r < 64 ? wf1[r * 160 + k] : ws1[(r - 64) * 160 + k]);
    wb2[i] = f2b(r < 64 ? wf2[r * 160 + k] : ws2[(r - 64) * 160 + k]);
}

__global__ void prep_x_kernel(const float4* __restrict__ x, unsigned short* __restrict__ xb) {
    int i = blockIdx.x * 256 + threadIdx.x;
    if (i >= N_NODES * 16) return;
    float4 v = x[i];
    ushort4 u; u.x = f2b(v.x); u.y = f2b(v.y); u.z = f2b(v.z); u.w = f2b(v.w);
    *(ushort4*)(xb + i * 4) = u;
}

__global__ void hist_kernel(const int* __restrict__ ei, int* __restrict__ cnt) {
    int i = blockIdx.x * 256 + threadIdx.x;
    if (i < N_EDGES) atomicAdd(&cnt[ei[N_EDGES + i]], 1);
}

__global__ void bsum_kernel(const int* __restrict__ cnt, int* __restrict__ bsum) {
    __shared__ int sm[256];
    int i = blockIdx.x * 256 + threadIdx.x;
    sm[threadIdx.x] = (i < N_NODES) ? cnt[i] : 0;
    __syncthreads();
    for (int off = 128; off > 0; off >>= 1) {
        if (threadIdx.x < off) sm[threadIdx.x] += sm[threadIdx.x + off];
        __syncthreads();
    }
    if (threadIdx.x == 0) bsum[blockIdx.x] = sm[0];
}

__global__ void bscan_kernel(const int* __restrict__ bsum, int* __restrict__ boffs) {
    __shared__ int sm[256];
    int t = threadIdx.x;
    int v = (t < NBS) ? bsum[t] : 0;
    sm[t] = v; __syncthreads();
    for (int off = 1; off < 256; off <<= 1) {
        int u = (t >= off) ? sm[t - off] : 0;
        __syncthreads();
        sm[t] += u;
        __syncthreads();
    }
    if (t < NBS) boffs[t] = sm[t] - v;  // exclusive
}

__global__ void apply_kernel(const int* __restrict__ cnt, const int* __restrict__ boffs,
                             int* __restrict__ cursor, float* __restrict__ invdeg) {
    __shared__ int sm[256];
    int t = threadIdx.x, i = blockIdx.x * 256 + t;
    int c = (i < N_NODES) ? cnt[i] : 0;
    sm[t] = c; __syncthreads();
    for (int off = 1; off < 256; off <<= 1) {
        int u = (t >= off) ? sm[t - off] : 0;
        __syncthreads();
        sm[t] += u;
        __syncthreads();
    }
    if (i < N_NODES) {
        cursor[i] = boffs[blockIdx.x] + sm[t] - c;
        invdeg[i] = 1.0f / fmaxf((float)c, 1.0f);
    }
}

// scatter + in-place sort of edge_attr to dst-order (bf16), fused
__global__ void scatter_kernel(const int* __restrict__ ei, int* __restrict__ cursor,
                               const float* __restrict__ ea,
                               int2* __restrict__ sed, unsigned short* __restrict__ eab) {
    int e = blockIdx.x * 256 + threadIdx.x;
    if (e >= N_EDGES) return;
    int s = ei[e], d = ei[N_EDGES + e];
    int p = atomicAdd(&cursor[d], 1);
    sed[p] = make_int2(s, d);
    const float4* src = (const float4*)(ea + (size_t)e * 32);
    unsigned short* dst = eab + (size_t)p * 32;
    #pragma unroll
    for (int j = 0; j < 8; ++j) {
        float4 v = src[j];
        ushort4 u; u.x = f2b(v.x); u.y = f2b(v.y); u.z = f2b(v.z); u.w = f2b(v.w);
        *(ushort4*)(dst + j * 4) = u;
    }
}

// ---------------- edge pass: in-register segmented reduction, no msg LDS ----------------
__global__ __launch_bounds__(256, 2)
void edge_mfma(const unsigned short* __restrict__ xb,
               const int2* __restrict__ sed, const unsigned short* __restrict__ eab,
               const unsigned short* __restrict__ wb,
               const float* __restrict__ bfv, const float* __restrict__ bsv,
               float* __restrict__ agg)
{
    __shared__ __align__(16) unsigned short Zd[2][64 * 64];  // chunk c of row e holds data chunk c^(e&7)
    __shared__ __align__(16) unsigned short Zs[2][64 * 64];
    __shared__ __align__(16) unsigned short Ze[2][64 * 32];  // chunk c holds data chunk c^((e>>1)&3)
    __shared__ int dstl[2][64];

    const int tid = threadIdx.x;
    const int w = tid >> 6, lane = tid & 63, lr = lane & 15, lq = lane >> 4;
    const int eh = (w >> 1) * 32, chh = (w & 1) * 32;

    bf16x8 B[2][2][5];
    #pragma unroll
    for (int mat = 0; mat < 2; ++mat)
        #pragma unroll
        for (int n = 0; n < 2; ++n)
            #pragma unroll
            for (int ks = 0; ks < 5; ++ks)
                B[mat][n][ks] = *(const bf16x8*)(wb + (size_t)(mat * 64 + chh + n * 16 + lr) * 160 + ks * 32 + lq * 8);

    float biasF[2], biasS[2];
    #pragma unroll
    for (int n = 0; n < 2; ++n) { biasF[n] = bfv[chh + n * 16 + lr]; biasS[n] = bsv[chh + n * 16 + lr]; }

    const int rA0 = tid >> 3, cA0 = tid & 7;
    const int rA1 = rA0 + 32;
    const int rE = tid >> 2, cE = tid & 3;
    const int dcA0 = cA0 ^ (rA0 & 7), dcA1 = cA0 ^ (rA1 & 7);
    const int dcE8 = (cE ^ ((rE >> 1) & 3)) * 8;

    const int NT = N_EDGES / 64;
    const int nblk = gridDim.x;

    bf16x8 vd0, vd1, vs0, vs1, veb;
    int dl = 0;

    // Early half: rows 0..31 of Zd/Zs + dstl (issued before k-loop)
    #define ISSUE_A(T) do { \
        int e0_ = (T) * 64; \
        int2 sA0 = sed[e0_ + rA0]; \
        vd0 = *(const bf16x8*)(xb + (size_t)sA0.y * 64 + dcA0 * 8); \
        vs0 = *(const bf16x8*)(xb + (size_t)sA0.x * 64 + dcA0 * 8); \
        if (tid < 64) dl = sed[e0_ + tid].y; \
    } while (0)
    // Late half: rows 32..63 + eab (issued after k-loop; lands before end-of-tile WRITE)
    #define ISSUE_B(T) do { \
        int e0_ = (T) * 64; \
        int2 sA1 = sed[e0_ + rA1]; \
        vd1 = *(const bf16x8*)(xb + (size_t)sA1.y * 64 + dcA1 * 8); \
        vs1 = *(const bf16x8*)(xb + (size_t)sA1.x * 64 + dcA1 * 8); \
        veb = *(const bf16x8*)(eab + (size_t)(e0_ + rE) * 32 + dcE8); \
    } while (0)

    #define WRITE(PAR) do { \
        *(bf16x8*)&Zd[PAR][rA0 * 64 + cA0 * 8] = vd0; \
        *(bf16x8*)&Zd[PAR][rA1 * 64 + cA0 * 8] = vd1; \
        *(bf16x8*)&Zs[PAR][rA0 * 64 + cA0 * 8] = vs0; \
        *(bf16x8*)&Zs[PAR][rA1 * 64 + cA0 * 8] = vs1; \
        *(bf16x8*)&Ze[PAR][rE * 32 + cE * 8] = veb; \
        if (tid < 64) dstl[PAR][tid] = dl; \
    } while (0)

    #define SOFT_BARRIER() do { \
        asm volatile("s_waitcnt lgkmcnt(0)" ::: "memory"); \
        __builtin_amdgcn_s_barrier(); \
    } while (0)

    int t = blockIdx.x;
    if (t < NT) { ISSUE_A(t); ISSUE_B(t); WRITE(0); }
    SOFT_BARRIER();
    int par = 0;

    for (; t < NT; t += nblk) {
        int tn = t + nblk;
        bool pf = tn < NT;
        if (pf) ISSUE_A(tn);

        // ---- k-loop (reads buf[par]) ----
        f32x4 aF[2][2] = {}; f32x4 aS[2][2] = {};
        const int r0 = eh + lr, r1 = eh + 16 + lr;
        #pragma unroll
        for (int ks = 0; ks < 5; ++ks) {
            bf16x8 a0, a1;
            if (ks < 2) {
                int j = ks * 4 + lq;
                a0 = *(const bf16x8*)&Zd[par][r0 * 64 + ((j ^ (r0 & 7)) * 8)];
                a1 = *(const bf16x8*)&Zd[par][r1 * 64 + ((j ^ (r1 & 7)) * 8)];
            } else if (ks < 4) {
                int j = (ks - 2) * 4 + lq;
                a0 = *(const bf16x8*)&Zs[par][r0 * 64 + ((j ^ (r0 & 7)) * 8)];
                a1 = *(const bf16x8*)&Zs[par][r1 * 64 + ((j ^ (r1 & 7)) * 8)];
            } else {
                a0 = *(const bf16x8*)&Ze[par][r0 * 32 + ((lq ^ ((r0 >> 1) & 3)) * 8)];
                a1 = *(const bf16x8*)&Ze[par][r1 * 32 + ((lq ^ ((r1 >> 1) & 3)) * 8)];
            }
            aF[0][0] = __builtin_amdgcn_mfma_f32_16x16x32_bf16(a0, B[0][0][ks], aF[0][0], 0, 0, 0);
            aF[0][1] = __builtin_amdgcn_mfma_f32_16x16x32_bf16(a0, B[0][1][ks], aF[0][1], 0, 0, 0);
            aF[1][0] = __builtin_amdgcn_mfma_f32_16x16x32_bf16(a1, B[0][0][ks], aF[1][0], 0, 0, 0);
            aF[1][1] = __builtin_amdgcn_mfma_f32_16x16x32_bf16(a1, B[0][1][ks], aF[1][1], 0, 0, 0);
            aS[0][0] = __builtin_amdgcn_mfma_f32_16x16x32_bf16(a0, B[1][0][ks], aS[0][0], 0, 0, 0);
            aS[0][1] = __builtin_amdgcn_mfma_f32_16x16x32_bf16(a0, B[1][1][ks], aS[0][1], 0, 0, 0);
            aS[1][0] = __builtin_amdgcn_mfma_f32_16x16x32_bf16(a1, B[1][0][ks], aS[1][0], 0, 0, 0);
            aS[1][1] = __builtin_amdgcn_mfma_f32_16x16x32_bf16(a1, B[1][1][ks], aS[1][1], 0, 0, 0);
        }

        if (pf) ISSUE_B(tn);  // late half: ~800+ cy until WRITE

        // ---- activation in registers (no LDS round-trip) ----
        float v0[8], v1[8];   // [m*4+i], n=0 / n=1; static indices only
        #pragma unroll
        for (int m = 0; m < 2; ++m)
            #pragma unroll
            for (int i = 0; i < 4; ++i) {
                {
                    float f = aF[m][0][i] + biasF[0];
                    float s = aS[m][0][i] + biasS[0];
                    float sig = RCPF(1.0f + __expf(-f));
                    float sp = fmaxf(s, 0.0f) + __logf(1.0f + __expf(-fabsf(s)));
                    v0[m * 4 + i] = sig * sp;
                }
                {
                    float f = aF[m][1][i] + biasF[1];
                    float s = aS[m][1][i] + biasS[1];
                    float sig = RCPF(1.0f + __expf(-f));
                    float sp = fmaxf(s, 0.0f) + __logf(1.0f + __expf(-fabsf(s)));
                    v1[m * 4 + i] = sig * sp;
                }
            }

        // ---- in-register segmented run-reduction over this wave's 32-edge quadrant ----
        {
            int rel = lane & 31;
            int dme = dstl[par][eh + rel];
            int dprev = (rel == 0) ? ~dme : dstl[par][eh + rel - 1];
            unsigned long long bmask = __ballot(dme != dprev) & 0xFFFFFFFFull;
            while (bmask) {
                int lo = (int)__builtin_ctzll(bmask);
                bmask &= bmask - 1;
                int hi = bmask ? (int)__builtin_ctzll(bmask) : 32;
                int dst = dstl[par][eh + lo];   // wave-uniform -> LDS broadcast
                float t0 = 0.0f, t1 = 0.0f;
                #pragma unroll
                for (int m = 0; m < 2; ++m)
                    #pragma unroll
                    for (int i = 0; i < 4; ++i) {
                        int r = m * 16 + lq * 4 + i;
                        bool in = (r >= lo) && (r < hi);
                        t0 += in ? v0[m * 4 + i] : 0.0f;
                        t1 += in ? v1[m * 4 + i] : 0.0f;
                    }
                t0 += __shfl_xor(t0, 16); t0 += __shfl_xor(t0, 32);
                t1 += __shfl_xor(t1, 16); t1 += __shfl_xor(t1, 32);
                if (lq < 2) {
                    int c = chh + (lq << 4) + lr;
                    float val = lq ? t1 : t0;
                    atomicAdd(&agg[(size_t)dst * 64 + c], val);
                }
            }
        }

        if (pf) WRITE(par ^ 1);
        SOFT_BARRIER();  // lgkm only: staged LDS visible; atomics/gathers stay in flight
        par ^= 1;
    }
    #undef ISSUE_A
    #undef ISSUE_B
    #undef WRITE
    #undef SOFT_BARRIER
}

// ---------------- residual: hb = bf16(agg*inv_deg + x) ----------------
__global__ void resid2_kernel(const float4* __restrict__ agg, const float* __restrict__ inv_deg,
                              const float4* __restrict__ x, unsigned short* __restrict__ hb)
{
    int i = blockIdx.x * 256 + threadIdx.x;
    if (i >= N_NODES * 16) return;
    int n = i >> 4;
    float iv = inv_deg[n];
    float4 a = agg[i], xv = x[i];
    ushort4 u;
    u.x = f2b(a.x * iv + xv.x); u.y = f2b(a.y * iv + xv.y);
    u.z = f2b(a.z * iv + xv.z); u.w = f2b(a.w * iv + xv.w);
    *(ushort4*)(hb + i * 4) = u;
}

// ---------------- layer-2 residual + pooling: run-reduction over SORTED batch ----------------
// Block: 64 nodes x 64 ch. Thread: ch = tid&63, sub-window = tid>>6 (16 nodes each).
__global__ void pool2_kernel(const float* __restrict__ agg, const float* __restrict__ inv_deg,
                             const unsigned short* __restrict__ hb, const int* __restrict__ batch,
                             float* __restrict__ gsum, float* __restrict__ gcnt)
{
    const int ch = threadIdx.x & 63, sub = threadIdx.x >> 6;
    const int base = blockIdx.x * 64 + sub * 16;
    float acc = 0.0f;
    int gcur = -1, rl = 0;
    #pragma unroll
    for (int j = 0; j < 16; ++j) {
        int n = base + j;
        if (n >= N_NODES) break;
        int g = batch[n];
        float v = agg[(size_t)n * 64 + ch] * inv_deg[n] + b2f(hb[(size_t)n * 64 + ch]);
        if (g != gcur) {
            if (gcur >= 0) {
                atomicAdd(&gsum[gcur * 64 + ch], acc);
                if (ch == 0) atomicAdd(&gcnt[gcur], (float)rl);
            }
            gcur = g; acc = v; rl = 1;
        } else {
            acc += v; rl++;
        }
    }
    if (gcur >= 0) {
        atomicAdd(&gsum[gcur * 64 + ch], acc);
        if (ch == 0) atomicAdd(&gcnt[gcur], (float)rl);
    }
}

// ---------------- head: MLP + log_softmax ----------------
__global__ __launch_bounds__(64)
void head_kernel(const float* __restrict__ gsum, const float* __restrict__ gcnt,
                 const float* __restrict__ w1, const float* __restrict__ b1,
                 const float* __restrict__ w2, const float* __restrict__ b2,
                 float* __restrict__ out)
{
    __shared__ float gv[64];
    __shared__ float hid[256];
    __shared__ float outv[16];
    const int g = blockIdx.x, t = threadIdx.x;
    float cnt = fmaxf(gcnt[g], 1.0f);
    gv[t] = gsum[g * 64 + t] / cnt;
    __syncthreads();
    #pragma unroll
    for (int r = 0; r < 4; ++r) {
        int c = t + r * 64;
        float acc = b1[c];
        const float4* wr = (const float4*)(w1 + c * 64);
        const float4* gvv = (const float4*)gv;
        #pragma unroll
        for (int k = 0; k < 16; ++k) {
            float4 wv = wr[k], xv = gvv[k];
            acc += wv.x * xv.x + wv.y * xv.y + wv.z * xv.z + wv.w * xv.w;
        }
        hid[c] = fmaxf(acc, 0.0f);
    }
    __syncthreads();
    if (t < 16) {
        float acc = b2[t];
        const float4* wr = (const float4*)(w2 + t * 256);
        const float4* hv = (const float4*)hid;
        for (int k = 0; k < 64; ++k) {
            float4 wv = wr[k], xv = hv[k];
            acc += wv.x * xv.x + wv.y * xv.y + wv.z * xv.z + wv.w * xv.w;
        }
        outv[t] = acc;
    }
    __syncthreads();
    if (t < 16) {
        float m = outv[0];
        #pragma unroll
        for (int j = 1; j < 16; ++j) m = fmaxf(m, outv[j]);
        float ssum = 0.0f;
        #pragma unroll
        for (int j = 0; j < 16; ++j) ssum += expf(outv[j] - m);
        out[g * 16 + t] = outv[t] - m - logf(ssum);
    }
}

extern "C" void kernel_launch(void* const* d_in, const int* in_sizes, int n_in,
                              void* d_out, int out_size, void* d_ws, size_t ws_size,
                              hipStream_t stream)
{
    const float* x     = (const float*)d_in[0];
    const int*   ei    = (const int*)d_in[1];
    const float* ea    = (const float*)d_in[2];
    const int*   batch = (const int*)d_in[3];
    const float* wf1 = (const float*)d_in[4];
    const float* bf1 = (const float*)d_in[5];
    const float* ws1 = (const float*)d_in[6];
    const float* bs1 = (const float*)d_in[7];
    const float* wf2 = (const float*)d_in[8];
    const float* bf2 = (const float*)d_in[9];
    const float* ws2 = (const float*)d_in[10];
    const float* bs2 = (const float*)d_in[11];
    const float* w1 = (const float*)d_in[12];
    const float* b1 = (const float*)d_in[13];
    const float* w2 = (const float*)d_in[14];
    const float* b2 = (const float*)d_in[15];
    float* out = (float*)d_out;

    char* ws = (char*)d_ws;
    int*   cnt    = (int*)(ws + 0x0000000);           // 200 KB
    int*   cursor = (int*)(ws + 0x0040000);           // 200 KB
    float* invdeg = (float*)(ws + 0x0080000);         // 200 KB
    int*   bsum   = (int*)(ws + 0x00C0000);           // 1 KB
    int*   boffs  = (int*)(ws + 0x00C1000);           // 1 KB
    int2*  sed    = (int2*)(ws + 0x0100000);          // 12.8 MB
    unsigned short* xb  = (unsigned short*)(ws + 0x1500000);  // 6.4 MB
    unsigned short* hb  = (unsigned short*)(ws + 0x1C00000);  // 6.4 MB
    float* agg = (float*)(ws + 0x2300000);            // 12.8 MB
    unsigned short* wb1 = (unsigned short*)(ws + 0x3000000);  // 40 KB
    unsigned short* wb2 = (unsigned short*)(ws + 0x3010000);  // 40 KB
    float* gsum = (float*)(ws + 0x3020000);           // 128 KB
    float* gcnt = (float*)(ws + 0x3040000);           // 2 KB
    unsigned short* eab = (unsigned short*)(ws + 0x3100000);  // 102.4 MB (fits: rounds 8-10 ran this path)

    hipMemsetAsync(cnt, 0, 200000, stream);
    hipMemsetAsync(agg, 0, 12800000, stream);
    hipMemsetAsync(gsum, 0, 131072 + 2048, stream);

    prep_w_kernel<<<80, 256, 0, stream>>>(wf1, ws1, wf2, ws2, wb1, wb2);
    prep_x_kernel<<<3125, 256, 0, stream>>>((const float4*)x, xb);
    hist_kernel<<<6250, 256, 0, stream>>>(ei, cnt);
    bsum_kernel<<<NBS, 256, 0, stream>>>(cnt, bsum);
    bscan_kernel<<<1, 256, 0, stream>>>(bsum, boffs);
    apply_kernel<<<NBS, 256, 0, stream>>>(cnt, boffs, cursor, invdeg);
    scatter_kernel<<<6250, 256, 0, stream>>>(ei, cursor, ea, sed, eab);

    edge_mfma<<<1024, 256, 0, stream>>>(xb, sed, eab, wb1, bf1, bs1, agg);
    resid2_kernel<<<3125, 256, 0, stream>>>((const float4*)agg, invdeg, (const float4*)x, hb);
    hipMemsetAsync(agg, 0, 12800000, stream);
    edge_mfma<<<1024, 256, 0, stream>>>(hb, sed, eab, wb2, bf2, bs2, agg);
    pool2_kernel<<<782, 256, 0, stream>>>(agg, invdeg, hb, batch, gsum, gcnt);
    head_kernel<<<NUM_GRAPHS, 64, 0, stream>>>(gsum, gcnt, w1, b1, w2, b2, out);
}